// Round 9
// baseline (141.679 us; speedup 1.0000x reference)
//
#include <hip/hip_runtime.h>

#define NN 50000
#define NE 800000
#define D  128
#define HB 128                     // hist/scatter blocks (chunks)
#define CH 6272                    // edges per chunk (128*6272 >= NE, mult of 4)
#define PW 50176                   // padded bin count (= 4*GRANGE = 98*512)
#define XB 128                     // xprep grid-stride blocks in prep kernel
#define RB2 98                     // reduce blocks (1024 thr) / scan blocks (512 thr)
#define GRANGE 12544               // gather src-range per pass (3.2 MB bf16 rows)

typedef short short8 __attribute__((ext_vector_type(8)));
typedef float f32x4  __attribute__((ext_vector_type(4)));
typedef unsigned char u8;

__device__ __forceinline__ ushort f2bf(float f) {
    union { float f; unsigned u; } v; v.f = f;
    unsigned r = v.u + 0x7FFFu + ((v.u >> 16) & 1u);   // RNE
    return (ushort)(r >> 16);
}

// ---------------- fused prep: hist (b<HB) | wprep (4 blocks) | xprep (XB blocks) ----------------

__global__ __launch_bounds__(1024) void prep_kernel(const int* __restrict__ src,
                                                    const int* __restrict__ dst,
                                                    const float* __restrict__ x,
                                                    const float* __restrict__ W1,
                                                    const float* __restrict__ W2,
                                                    u8* __restrict__ psrc,
                                                    u8* __restrict__ pdst,
                                                    ushort* __restrict__ xbf,
                                                    ushort* __restrict__ W1t,
                                                    ushort* __restrict__ W2t) {
    __shared__ unsigned bins[2 * PW / 4];      // 100,352 B (hist blocks only)
    const int t = threadIdx.x, b = blockIdx.x;

    if (b < HB) {
        for (int i = t; i < 2 * PW / 16; i += 1024)
            ((uint4*)bins)[i] = make_uint4(0, 0, 0, 0);
        __syncthreads();
        const int base = b * CH;
#pragma unroll
        for (int i = 0; i < 2; ++i) {          // CH = 6272 <= 2*4096
            int e0 = base + i * 4096 + t * 4;
            if (e0 < base + CH && e0 < NE) {
                int4 s4 = *(const int4*)(src + e0);
                int4 d4 = *(const int4*)(dst + e0);
                atomicAdd(&bins[s4.x >> 2], 1u << ((s4.x & 3) << 3));
                atomicAdd(&bins[s4.y >> 2], 1u << ((s4.y & 3) << 3));
                atomicAdd(&bins[s4.z >> 2], 1u << ((s4.z & 3) << 3));
                atomicAdd(&bins[s4.w >> 2], 1u << ((s4.w & 3) << 3));
                atomicAdd(&bins[PW / 4 + (d4.x >> 2)], 1u << ((d4.x & 3) << 3));
                atomicAdd(&bins[PW / 4 + (d4.y >> 2)], 1u << ((d4.y & 3) << 3));
                atomicAdd(&bins[PW / 4 + (d4.z >> 2)], 1u << ((d4.z & 3) << 3));
                atomicAdd(&bins[PW / 4 + (d4.w >> 2)], 1u << ((d4.w & 3) << 3));
            }
        }
        __syncthreads();
        uint4* os = (uint4*)(psrc + (size_t)b * PW);
        uint4* od = (uint4*)(pdst + (size_t)b * PW);
        for (int i = t; i < PW / 16; i += 1024) {
            os[i] = ((const uint4*)bins)[i];
            od[i] = ((const uint4*)(bins + PW / 4))[i];
        }
    } else if (b < HB + 4) {
        // wprep: f32 W[k][n] -> bf16 Wt[n][k]
        int c = (b - HB) * 1024 + t;
        if (c < 4096) {
            const float* W = (c < 2048) ? W1 : W2;
            ushort* Wt     = (c < 2048) ? W1t : W2t;
            int cc = c & 2047;
            int n  = cc >> 4;
            int k0 = (cc & 15) * 8;
            ushort tmp[8];
#pragma unroll
            for (int j = 0; j < 8; ++j) tmp[j] = f2bf(W[(k0 + j) * D + n]);
            *reinterpret_cast<uint4*>(Wt + n * D + k0) = *reinterpret_cast<uint4*>(tmp);
        }
    } else {
        // xprep: x -> bf16, grid-stride
        for (int i = (b - HB - 4) * 1024 + t; i < NN * D / 8; i += XB * 1024) {
            const float4* p = (const float4*)(x + (size_t)i * 8);
            float4 v0 = p[0], v1 = p[1];
            ushort tmp[8];
            tmp[0] = f2bf(v0.x); tmp[1] = f2bf(v0.y); tmp[2] = f2bf(v0.z); tmp[3] = f2bf(v0.w);
            tmp[4] = f2bf(v1.x); tmp[5] = f2bf(v1.y); tmp[6] = f2bf(v1.z); tmp[7] = f2bf(v1.w);
            *reinterpret_cast<uint4*>(xbf + (size_t)i * 8) = *reinterpret_cast<uint4*>(tmp);
        }
    }
}

// standalone xprep (fallback when xbf overlays psrc: must run after scatter)
__global__ __launch_bounds__(256) void xprep_kernel(const float* __restrict__ x,
                                                    ushort* __restrict__ xbf) {
    int i = blockIdx.x * 256 + threadIdx.x;
    if (i >= NN * D / 8) return;
    const float4* p = (const float4*)(x + (size_t)i * 8);
    float4 v0 = p[0], v1 = p[1];
    ushort tmp[8];
    tmp[0] = f2bf(v0.x); tmp[1] = f2bf(v0.y); tmp[2] = f2bf(v0.z); tmp[3] = f2bf(v0.w);
    tmp[4] = f2bf(v1.x); tmp[5] = f2bf(v1.y); tmp[6] = f2bf(v1.z); tmp[7] = f2bf(v1.w);
    *reinterpret_cast<uint4*>(xbf + (size_t)i * 8) = *reinterpret_cast<uint4*>(tmp);
}

// ---------------- reduce (8x parallel): deg->rsq, cnt, in-place prefix of pdst, block sums ----
// Thread (g, c): node-quad g < PW/4, chunk c < 8 covering blocks [c*16, c*16+16).
// Packed u8 quads processed as two 16-bit-field u32 accumulators (no carry: <= 32640).

__global__ __launch_bounds__(1024) void reduce_kernel(const unsigned* __restrict__ psrc32,
                                                      unsigned* __restrict__ pdst32,
                                                      float* __restrict__ rsq,
                                                      int* __restrict__ cnt,
                                                      int* __restrict__ bsum98) {
    __shared__ int sm[128];
    const int t = threadIdx.x;
    const int g = (blockIdx.x * 1024 + t) >> 3;  // node-quad, < 12544
    const int c = t & 7;
    const size_t stride = PW / 4;

    unsigned wv[16];
#pragma unroll
    for (int i = 0; i < 16; ++i)
        wv[i] = pdst32[(size_t)(c * 16 + i) * stride + g];
    unsigned t02 = 0, t13 = 0;
#pragma unroll
    for (int i = 0; i < 16; ++i) {
        t02 += wv[i] & 0x00FF00FFu;
        t13 += (wv[i] >> 8) & 0x00FF00FFu;
    }
    unsigned p02 = 0, p13 = 0;
#pragma unroll
    for (int i = 0; i < 16; ++i) {
        unsigned w = psrc32[(size_t)(c * 16 + i) * stride + g];
        p02 += w & 0x00FF00FFu;
        p13 += (w >> 8) & 0x00FF00FFu;
    }
    // inclusive scan of chunk sums across the 8 lanes of this node-quad
    unsigned i02 = t02, i13 = t13;
#pragma unroll
    for (int off = 1; off < 8; off <<= 1) {
        unsigned v02 = __shfl_up(i02, off, 8);
        unsigned v13 = __shfl_up(i13, off, 8);
        if (c >= off) { i02 += v02; i13 += v13; }
    }
    // butterfly totals (src degree, dst count)
    unsigned q02 = p02, q13 = p13, u02 = t02, u13 = t13;
#pragma unroll
    for (int off = 1; off < 8; off <<= 1) {
        q02 += __shfl_xor(q02, off, 8);
        q13 += __shfl_xor(q13, off, 8);
        u02 += __shfl_xor(u02, off, 8);
        u13 += __shfl_xor(u13, off, 8);
    }
    // rewrite pdst with running exclusive prefix
    unsigned r02 = i02 - t02, r13 = i13 - t13;
#pragma unroll
    for (int i = 0; i < 16; ++i) {
        unsigned w = wv[i];
        pdst32[(size_t)(c * 16 + i) * stride + g] =
            (r02 & 0xFFu) | ((r13 & 0xFFu) << 8) |
            (r02 & 0x00FF0000u) | ((r13 & 0x00FF0000u) << 8);
        r02 += w & 0x00FF00FFu;
        r13 += (w >> 8) & 0x00FF00FFu;
    }
    int tct = 0;
    if (c == 0) {
        int v0 = g * 4;
        int dg_[4] = { (int)(q02 & 0xFFFFu), (int)(q13 & 0xFFFFu),
                       (int)(q02 >> 16),     (int)(q13 >> 16) };
        int ct_[4] = { (int)(u02 & 0xFFFFu), (int)(u13 & 0xFFFFu),
                       (int)(u02 >> 16),     (int)(u13 >> 16) };
        tct = ct_[0] + ct_[1] + ct_[2] + ct_[3];   // pads count 0 (dst < NN always)
        if (v0 + 3 < NN) {
            *(float4*)(rsq + v0) = make_float4(rsqrtf(fmaxf((float)dg_[0], 1.f)),
                                               rsqrtf(fmaxf((float)dg_[1], 1.f)),
                                               rsqrtf(fmaxf((float)dg_[2], 1.f)),
                                               rsqrtf(fmaxf((float)dg_[3], 1.f)));
            *(int4*)(cnt + v0) = make_int4(ct_[0], ct_[1], ct_[2], ct_[3]);
        } else {
            for (int j = 0; j < 4; ++j)
                if (v0 + j < NN) {
                    rsq[v0 + j] = rsqrtf(fmaxf((float)dg_[j], 1.f));
                    cnt[v0 + j] = ct_[j];
                }
        }
        sm[t >> 3] = tct;
    }
    __syncthreads();
    for (int s = 64; s > 0; s >>= 1) {
        if (t < s) sm[t] += sm[t + s];
        __syncthreads();
    }
    if (t == 0) bsum98[blockIdx.x] = sm[0];
}

// ---------------- scan_write: offs from cnt + bsum98 (base computed in-kernel) ----------------

__global__ __launch_bounds__(512) void scan_write(const int* __restrict__ cnt,
                                                  const int* __restrict__ bsum98,
                                                  int* __restrict__ offs) {
    __shared__ int sm[512];
    const int b = blockIdx.x, t = threadIdx.x;
    sm[t] = (t < RB2 && t < b) ? bsum98[t] : 0;
    __syncthreads();
    for (int s = 256; s > 0; s >>= 1) {
        if (t < s) sm[t] += sm[t + s];
        __syncthreads();
    }
    int base = sm[0];
    __syncthreads();
    int i = b * 512 + t;
    int v = (i < NN) ? cnt[i] : 0;
    sm[t] = v;
    __syncthreads();
    for (int d2 = 1; d2 < 512; d2 <<= 1) {
        int u = (t >= d2) ? sm[t - d2] : 0;
        __syncthreads();
        sm[t] += u;
        __syncthreads();
    }
    if (i < NN) offs[i] = base + sm[t] - v;
    if (b == 0 && t == 0) offs[NN] = NE;
}

// ---------------- scatter: CSR fill, u8 LDS cursors, packed 4B entries ----------------

__global__ __launch_bounds__(1024) void scatter_kernel(const int* __restrict__ src,
                                                       const int* __restrict__ dst,
                                                       const float* __restrict__ ew,
                                                       const float* __restrict__ rsq,
                                                       const int* __restrict__ offs,
                                                       const u8* __restrict__ pd,
                                                       unsigned* __restrict__ csr) {
    __shared__ unsigned cur[PW / 4];           // 50,176 B packed u8 cursors
    const int t = threadIdx.x, b = blockIdx.x;
    for (int i = t; i < PW / 16; i += 1024)
        ((uint4*)cur)[i] = make_uint4(0, 0, 0, 0);
    __syncthreads();

    const u8* pdrow = pd + (size_t)b * PW;
    const int base = b * CH;
#pragma unroll
    for (int i = 0; i < 2; ++i) {
        int e0 = base + i * 4096 + t * 4;
        if (e0 < base + CH && e0 < NE) {
            int4 s4 = *(const int4*)(src + e0);
            int4 d4 = *(const int4*)(dst + e0);
            float4 w4 = *(const float4*)(ew + e0);
#pragma unroll
            for (int j = 0; j < 4; ++j) {
                int s = (j == 0) ? s4.x : (j == 1) ? s4.y : (j == 2) ? s4.z : s4.w;
                int d = (j == 0) ? d4.x : (j == 1) ? d4.y : (j == 2) ? d4.z : d4.w;
                float w = (j == 0) ? w4.x : (j == 1) ? w4.y : (j == 2) ? w4.z : w4.w;
                int sh = (d & 3) << 3;
                unsigned old = atomicAdd(&cur[d >> 2], 1u << sh);
                int rel = (int)((old >> sh) & 0xFFu);
                int pos = offs[d] + (int)pdrow[d] + rel;
                float coef = rsq[s] * rsq[d] * w;
                csr[pos] = (unsigned)s | ((unsigned)f2bf(coef) << 16);
            }
        }
    }
}

// ---------------- aggregation: 4-pass src-range for L2 locality ----------------
// Pass p touches only x rows [p*GRANGE, (p+1)*GRANGE) (3.2 MB bf16 <= 4 MB XCD L2).
// Ballot selects in-range edges; shfl count stays ~NE total (skips cost no LDS op).

__global__ __launch_bounds__(256) void gather_bf16_kernel(const int* __restrict__ offs,
                                                          const unsigned* __restrict__ csr,
                                                          const ushort* __restrict__ xbf,
                                                          float* __restrict__ agg) {
    int v = blockIdx.x * 8 + (threadIdx.x >> 5);
    if (v >= NN) return;
    const int lane = threadIdx.x & 31;
    const int half = (threadIdx.x >> 5) & 1;     // this group's half of the wave
    const int beg = offs[v], end = offs[v + 1];
    float a0 = 0.f, a1 = 0.f, a2 = 0.f, a3 = 0.f;
#pragma unroll
    for (int p = 0; p < 4; ++p) {
        const unsigned lo = p * GRANGE;
        for (int i0 = beg; i0 < end; i0 += 32) {
            int n = end - i0; if (n > 32) n = 32;
            unsigned ej = (lane < n) ? csr[i0 + lane] : 0u;
            bool inr = (lane < n) && ((unsigned)(ej & 0xFFFFu) - lo < (unsigned)GRANGE);
            unsigned m = (unsigned)(__ballot(inr) >> (half * 32));
            while (m) {
                int j = __builtin_ctz(m); m &= m - 1;
                unsigned e = __shfl(ej, j, 32);
                float c = __int_as_float(e & 0xFFFF0000u);      // bf16 coef
                uint2 u = ((const uint2*)(xbf + (size_t)(e & 0xFFFFu) * D))[lane];
                a0 = fmaf(__int_as_float((int)(u.x << 16)),         c, a0);
                a1 = fmaf(__int_as_float((int)(u.x & 0xFFFF0000u)), c, a1);
                a2 = fmaf(__int_as_float((int)(u.y << 16)),         c, a2);
                a3 = fmaf(__int_as_float((int)(u.y & 0xFFFF0000u)), c, a3);
            }
        }
    }
    ((float4*)(agg + (size_t)v * D))[lane] = make_float4(a0, a1, a2, a3);
}

// ---------------- fused FFN via bf16 MFMA (unchanged) ----------------

__global__ __launch_bounds__(256) void ffn_mfma_kernel(const float* __restrict__ agg,
                                                       const ushort* __restrict__ W1t,
                                                       const ushort* __restrict__ W2t,
                                                       const float* __restrict__ b1,
                                                       const float* __restrict__ b2,
                                                       float* __restrict__ out) {
    __shared__ ushort Wt[128 * 128];
    __shared__ ushort hS[4][16 * 128];

    const int t  = threadIdx.x;
    const int w  = t >> 6;
    const int l  = t & 63;
    const int lr = l & 15;
    const int lk = l >> 4;
    const int r0 = blockIdx.x * 64;

    for (int i = 0; i < 8; ++i) {
        int c = i * 256 + t;
        int n = c >> 4;
        int slot = c & 15;
        uint4 v = ((const uint4*)W1t)[c];
        int byte = n * 256 + ((slot * 16) ^ ((n & 7) << 4));
        *(uint4*)((char*)Wt + byte) = v;
    }

    const int arow = r0 + w * 16 + lr;
    short8 afrag[4];
#pragma unroll
    for (int kb = 0; kb < 4; ++kb) {
        int k = kb * 32 + lk * 8;
        float4 v0 = make_float4(0.f, 0.f, 0.f, 0.f), v1 = v0;
        if (arow < NN) {
            const float4* ap = (const float4*)(agg + (size_t)arow * D + k);
            v0 = ap[0]; v1 = ap[1];
        }
        short8 a;
        a[0] = (short)f2bf(v0.x); a[1] = (short)f2bf(v0.y);
        a[2] = (short)f2bf(v0.z); a[3] = (short)f2bf(v0.w);
        a[4] = (short)f2bf(v1.x); a[5] = (short)f2bf(v1.y);
        a[6] = (short)f2bf(v1.z); a[7] = (short)f2bf(v1.w);
        afrag[kb] = a;
    }
    __syncthreads();

    f32x4 acc[8];
#pragma unroll
    for (int nt = 0; nt < 8; ++nt) acc[nt] = (f32x4){0.f, 0.f, 0.f, 0.f};
#pragma unroll
    for (int kb = 0; kb < 4; ++kb) {
        int kbyte = (kb * 32 + lk * 8) * 2;
#pragma unroll
        for (int nt = 0; nt < 8; ++nt) {
            int n = nt * 16 + lr;
            short8 b = *(const short8*)((const char*)Wt + n * 256 + (kbyte ^ ((n & 7) << 4)));
            acc[nt] = __builtin_amdgcn_mfma_f32_16x16x32_bf16(afrag[kb], b, acc[nt], 0, 0, 0);
        }
    }
#pragma unroll
    for (int nt = 0; nt < 8; ++nt) {
        int col = nt * 16 + lr;
        float bb = b1[col];
#pragma unroll
        for (int r = 0; r < 4; ++r) {
            int row = lk * 4 + r;
            float h = fmaxf(acc[nt][r] + bb, 0.0f);
            int byte = row * 256 + ((col * 2) ^ ((row & 7) << 4));
            *(ushort*)((char*)&hS[w][0] + byte) = f2bf(h);
        }
    }
    __syncthreads();

    for (int i = 0; i < 8; ++i) {
        int c = i * 256 + t;
        int n = c >> 4;
        int slot = c & 15;
        uint4 v = ((const uint4*)W2t)[c];
        int byte = n * 256 + ((slot * 16) ^ ((n & 7) << 4));
        *(uint4*)((char*)Wt + byte) = v;
    }
    __syncthreads();

    short8 hfrag[4];
#pragma unroll
    for (int kb = 0; kb < 4; ++kb) {
        int kbyte = (kb * 32 + lk * 8) * 2;
        hfrag[kb] = *(const short8*)((const char*)&hS[w][0] + lr * 256 + (kbyte ^ ((lr & 7) << 4)));
    }
#pragma unroll
    for (int nt = 0; nt < 8; ++nt) acc[nt] = (f32x4){0.f, 0.f, 0.f, 0.f};
#pragma unroll
    for (int kb = 0; kb < 4; ++kb) {
        int kbyte = (kb * 32 + lk * 8) * 2;
#pragma unroll
        for (int nt = 0; nt < 8; ++nt) {
            int n = nt * 16 + lr;
            short8 b = *(const short8*)((const char*)Wt + n * 256 + (kbyte ^ ((n & 7) << 4)));
            acc[nt] = __builtin_amdgcn_mfma_f32_16x16x32_bf16(hfrag[kb], b, acc[nt], 0, 0, 0);
        }
    }
#pragma unroll
    for (int nt = 0; nt < 8; ++nt) {
        int col = nt * 16 + lr;
        float bb = b2[col];
#pragma unroll
        for (int r = 0; r < 4; ++r) {
            int row = r0 + w * 16 + lk * 4 + r;
            if (row < NN) out[(size_t)row * D + col] = acc[nt][r] + bb;
        }
    }
}

// ---------------- launch ----------------

extern "C" void kernel_launch(void* const* d_in, const int* in_sizes, int n_in,
                              void* d_out, int out_size, void* d_ws, size_t ws_size,
                              hipStream_t stream) {
    const float* x  = (const float*)d_in[0];
    const int* src  = (const int*)d_in[1];
    const int* dst  = (const int*)d_in[2];
    const float* ew = (const float*)d_in[3];
    const float* W1 = (const float*)d_in[4];
    const float* b1 = (const float*)d_in[5];
    const float* W2 = (const float*)d_in[6];
    const float* b2 = (const float*)d_in[7];
    float* out = (float*)d_out;

    // workspace layout (16B-aligned), ~29.5 MB with dedicated xbf
    char* base = (char*)d_ws;
    size_t off = 0;
    auto alloc = [&](size_t bytes) { char* p = base + off; off = (off + bytes + 15) & ~(size_t)15; return p; };
    u8* psrc      = (u8*)alloc((size_t)HB * PW);         // src partial hists (u8)
    u8* pdst      = (u8*)alloc((size_t)HB * PW);         // dst partials -> before[b][v]
    float* rsq    = (float*)alloc((size_t)NN * 4);
    int* cnt      = (int*)alloc((size_t)NN * 4);
    int* offs     = (int*)alloc((size_t)(NN + 1) * 4);
    int* bsum98   = (int*)alloc((size_t)RB2 * 4);
    unsigned* csr = (unsigned*)alloc((size_t)NE * 4);    // packed src|coef
    ushort* W1t   = (ushort*)alloc((size_t)D * D * 2);
    ushort* W2t   = (ushort*)alloc((size_t)D * D * 2);
    ushort* xbf_own = (ushort*)alloc((size_t)NN * D * 2);
    bool own_xbf = ws_size >= off;                       // dedicated xbf fits?
    ushort* xbf = own_xbf ? xbf_own : (ushort*)psrc;     // else overlay (post-scatter)

    int prep_grid = own_xbf ? (HB + 4 + XB) : (HB + 4);
    prep_kernel<<<prep_grid, 1024, 0, stream>>>(src, dst, x, W1, W2,
                                                psrc, pdst, xbf, W1t, W2t);
    reduce_kernel<<<RB2, 1024, 0, stream>>>((const unsigned*)psrc, (unsigned*)pdst,
                                            rsq, cnt, bsum98);
    scan_write<<<RB2, 512, 0, stream>>>(cnt, bsum98, offs);
    scatter_kernel<<<HB, 1024, 0, stream>>>(src, dst, ew, rsq, offs, pdst, csr);
    if (!own_xbf)  // overlay: psrc/pdst dead only after scatter
        xprep_kernel<<<(NN * D / 8 + 255) / 256, 256, 0, stream>>>(x, xbf);
    // agg lives in d_out
    gather_bf16_kernel<<<(NN + 7) / 8, 256, 0, stream>>>(offs, csr, xbf, out);
    ffn_mfma_kernel<<<(NN + 63) / 64, 256, 0, stream>>>(out, W1t, W2t, b1, b2, out);
}